// Round 1
// baseline (305.453 us; speedup 1.0000x reference)
//
#include <hip/hip_runtime.h>

#define B_  8
#define C_  256
#define N_  16384
#define NM_ 128
#define TS  128
#define KB  32

// ---------------- kernel 1: row squared norms of X and Y ----------------
__global__ __launch_bounds__(256) void norms_kernel(const float* __restrict__ X,
                                                    const float* __restrict__ Y,
                                                    float* __restrict__ x2,
                                                    float* __restrict__ y2) {
    int row = blockIdx.x;
    const float* src;
    float* dst;
    if (row < B_ * C_) { src = X + (size_t)row * N_; dst = x2 + row; }
    else { int r = row - B_ * C_; src = Y + (size_t)r * N_; dst = y2 + r; }

    const float4* s4 = (const float4*)src;
    float s = 0.f;
    for (int i = threadIdx.x; i < N_ / 4; i += 256) {
        float4 v = s4[i];
        s += v.x * v.x + v.y * v.y + v.z * v.z + v.w * v.w;
    }
#pragma unroll
    for (int off = 32; off > 0; off >>= 1) s += __shfl_down(s, off);
    __shared__ float wsum[4];
    int lane = threadIdx.x & 63, wid = threadIdx.x >> 6;
    if (lane == 0) wsum[wid] = s;
    __syncthreads();
    if (threadIdx.x == 0) *dst = wsum[0] + wsum[1] + wsum[2] + wsum[3];
}

// ---------------- kernel 2: split-K fp32 GEMM  Gp[ks,b,i,j] = sum_k x[b,i,k]*y[b,j,k] ----------------
__global__ __launch_bounds__(256) void gemm_part_kernel(const float* __restrict__ X,
                                                        const float* __restrict__ Y,
                                                        float* __restrict__ Gp,
                                                        int Kchunk) {
    __shared__ float xs[KB][TS];
    __shared__ float ys[KB][TS];

    int lin = blockIdx.x;
    int jt = lin & 1, it = (lin >> 1) & 1, b = (lin >> 2) & 7, ks = lin >> 5;

    const float* xb = X + ((size_t)b * C_ + (size_t)it * TS) * N_;
    const float* yb = Y + ((size_t)b * C_ + (size_t)jt * TS) * N_;

    int tid = threadIdx.x;
    int tx = tid & 15, ty = tid >> 4;
    int lrow = tid >> 1;           // 0..127
    int lq = (tid & 1) * 16;       // 0 or 16 (column sub-chunk)

    float acc[8][8] = {};
    int k0 = ks * Kchunk;

    for (int kk = 0; kk < Kchunk; kk += KB) {
        __syncthreads();
        // stage KB x TS tiles of X and Y (transposed: xs[k][row]) into LDS
        float vx[16], vy[16];
        const float4* xsrc = (const float4*)(xb + (size_t)lrow * N_ + k0 + kk + lq);
        const float4* ysrc = (const float4*)(yb + (size_t)lrow * N_ + k0 + kk + lq);
#pragma unroll
        for (int q = 0; q < 4; ++q) ((float4*)vx)[q] = xsrc[q];
#pragma unroll
        for (int q = 0; q < 4; ++q) ((float4*)vy)[q] = ysrc[q];
#pragma unroll
        for (int w = 0; w < 16; ++w) {
            xs[lq + w][lrow] = vx[w];
            ys[lq + w][lrow] = vy[w];
        }
        __syncthreads();

#pragma unroll 8
        for (int k = 0; k < KB; ++k) {
            float a[8], bb[8];
#pragma unroll
            for (int r = 0; r < 8; ++r) a[r] = xs[k][ty * 8 + r];
#pragma unroll
            for (int c = 0; c < 8; ++c) bb[c] = ys[k][tx * 8 + c];
#pragma unroll
            for (int r = 0; r < 8; ++r)
#pragma unroll
                for (int c = 0; c < 8; ++c)
                    acc[r][c] = fmaf(a[r], bb[c], acc[r][c]);
        }
    }

    size_t gbase = (((size_t)ks * B_ + b) * C_ + (size_t)(it * TS + ty * 8)) * C_
                 + jt * TS + tx * 8;
#pragma unroll
    for (int r = 0; r < 8; ++r) {
        float4 v0 = make_float4(acc[r][0], acc[r][1], acc[r][2], acc[r][3]);
        float4 v1 = make_float4(acc[r][4], acc[r][5], acc[r][6], acc[r][7]);
        *(float4*)&Gp[gbase + (size_t)r * C_]     = v0;
        *(float4*)&Gp[gbase + (size_t)r * C_ + 4] = v1;
    }
}

// ---------------- kernel 3: reduce split-K, d2 = x2+y2-2G, argmin over j (tie -> smaller j) ----------------
__global__ __launch_bounds__(256) void argmin_kernel(const float* __restrict__ Gp,
                                                     const float* __restrict__ x2,
                                                     const float* __restrict__ y2,
                                                     float* __restrict__ minval,
                                                     int* __restrict__ minidx,
                                                     int KS) {
    int bi = blockIdx.x;           // b*C + i
    int b = bi >> 8;
    int i = bi & 255;
    int j = threadIdx.x;           // 0..255 == C

    float g = 0.f;
    for (int ks = 0; ks < KS; ++ks)
        g += Gp[(((size_t)ks * B_ + b) * C_ + i) * C_ + j];

    float v = x2[bi] + y2[b * C_ + j] - 2.f * g;
    int idx = j;
#pragma unroll
    for (int off = 32; off > 0; off >>= 1) {
        float v2 = __shfl_down(v, off);
        int i2 = __shfl_down(idx, off);
        if (v2 < v || (v2 == v && i2 < idx)) { v = v2; idx = i2; }
    }
    __shared__ float wv[4];
    __shared__ int wi[4];
    int lane = threadIdx.x & 63, wid = threadIdx.x >> 6;
    if (lane == 0) { wv[wid] = v; wi[wid] = idx; }
    __syncthreads();
    if (threadIdx.x == 0) {
        for (int w = 1; w < 4; ++w)
            if (wv[w] < v || (wv[w] == v && wi[w] < idx)) { v = wv[w]; idx = wi[w]; }
        minval[bi] = v;
        minidx[bi] = idx;
    }
}

// ---------------- kernel 4: per-batch stable top-128 selection + compaction ----------------
__global__ __launch_bounds__(256) void select_kernel(const float* __restrict__ minval,
                                                     const int* __restrict__ minidx,
                                                     int* __restrict__ nn) {
    int b = blockIdx.x;
    int i = threadIdx.x;           // channel
    __shared__ float vals[C_];
    __shared__ int wcnt[4];

    float v = minval[b * C_ + i];
    vals[i] = v;
    __syncthreads();

    // stable rank: (value, index) lexicographic
    int rank = 0;
    for (int t = 0; t < C_; ++t) {
        float u = vals[t];
        rank += (u < v) || (u == v && t < i);
    }
    bool flag = rank < NM_;

    unsigned long long m = __ballot(flag);
    int lane = i & 63, wid = i >> 6;
    if (lane == 0) wcnt[wid] = (int)__popcll(m);
    __syncthreads();
    int off = 0;
    for (int w = 0; w < wid; ++w) off += wcnt[w];
    int pos = off + (int)__popcll(m & ((1ULL << lane) - 1ULL));
    if (flag) nn[b * NM_ + pos] = minidx[b * C_ + i];
}

// ---------------- kernel 5: gather selected Ym rows ----------------
__global__ __launch_bounds__(256) void gather_kernel(const float* __restrict__ Y,
                                                     const int* __restrict__ nn,
                                                     float* __restrict__ out) {
    int blk = blockIdx.x;
    int b = blk >> 7;
    int m = blk & 127;
    int src = nn[b * NM_ + m];
    const float4* s = (const float4*)(Y + ((size_t)b * C_ + src) * N_);
    float4* d = (float4*)(out + ((size_t)b * NM_ + m) * N_);
    for (int t = threadIdx.x; t < N_ / 4; t += 256) d[t] = s[t];
}

extern "C" void kernel_launch(void* const* d_in, const int* in_sizes, int n_in,
                              void* d_out, int out_size, void* d_ws, size_t ws_size,
                              hipStream_t stream) {
    const float* X = (const float*)d_in[0];
    const float* Y = (const float*)d_in[1];
    float* out = (float*)d_out;

    // workspace layout (floats): x2[2048] y2[2048] minval[2048] minidx[2048] nn[1024] Gp[KS*8*256*256]
    float* x2 = (float*)d_ws;
    float* y2 = x2 + B_ * C_;
    float* minval = y2 + B_ * C_;
    int* minidx = (int*)(minval + B_ * C_);
    int* nn = minidx + B_ * C_;
    float* Gp = (float*)(nn + B_ * NM_);

    size_t head = (size_t)(B_ * C_) * 4 + B_ * NM_;
    size_t favail = ws_size / 4;
    size_t gavail = favail > head ? favail - head : 0;
    int KS = 1;
    while (KS < 16 && (size_t)(KS * 2) * B_ * C_ * C_ <= gavail) KS *= 2;
    int Kchunk = N_ / KS;

    hipLaunchKernelGGL(norms_kernel, dim3(2 * B_ * C_), dim3(256), 0, stream, X, Y, x2, y2);
    hipLaunchKernelGGL(gemm_part_kernel, dim3(KS * 32), dim3(256), 0, stream, X, Y, Gp, Kchunk);
    hipLaunchKernelGGL(argmin_kernel, dim3(B_ * C_), dim3(256), 0, stream, Gp, x2, y2, minval, minidx, KS);
    hipLaunchKernelGGL(select_kernel, dim3(B_), dim3(256), 0, stream, minval, minidx, nn);
    hipLaunchKernelGGL(gather_kernel, dim3(B_ * NM_), dim3(256), 0, stream, Y, nn, out);
}

// Round 2
// 132.703 us; speedup vs baseline: 2.3018x; 2.3018x over previous
//
#include <hip/hip_runtime.h>

#define B_  8
#define C_  256
#define N_  16384
#define NM_ 128

typedef _Float16 f16x8 __attribute__((ext_vector_type(8)));
typedef float    f32x4 __attribute__((ext_vector_type(4)));

#define LDK 40   // padded row stride (halves): 80B -> 20-bank lane stride, conflict-free

// ---------------- kernel 1: split-K fp16x2 MFMA GEMM + fused norm partials ----------------
// Gp[ks,b,i,j] = sum_{k in chunk} x[b,i,k]*y[b,j,k]  (hi*hi + hi*lo + lo*hi)
// x2p[ks,b,i], y2p[ks,b,j] = per-chunk squared-norm partials (fp32, from staged data)
__global__ __launch_bounds__(256) void gemm_f16_kernel(const float* __restrict__ X,
                                                       const float* __restrict__ Y,
                                                       float* __restrict__ Gp,
                                                       float* __restrict__ x2p,
                                                       float* __restrict__ y2p,
                                                       int Kchunk) {
    __shared__ _Float16 aH[128][LDK];
    __shared__ _Float16 aL[128][LDK];
    __shared__ _Float16 bH[128][LDK];
    __shared__ _Float16 bL[128][LDK];

    int lin = blockIdx.x;
    int jt = lin & 1, it = (lin >> 1) & 1, b = (lin >> 2) & 7, ks = lin >> 5;
    int k0 = ks * Kchunk;

    int t = threadIdx.x;
    int lane = t & 63;
    int wid = t >> 6;            // 4 waves
    int wm = wid >> 1, wn = wid & 1;  // wave tile: rows wm*64.., cols wn*64..

    int srow = t >> 1;           // staging row 0..127
    int skq = (t & 1) * 16;      // staging k sub-chunk 0 or 16

    const float* xp = X + ((size_t)(b * C_) + it * 128 + srow) * N_ + k0 + skq;
    const float* yp = Y + ((size_t)(b * C_) + jt * 128 + srow) * N_ + k0 + skq;

    f32x4 acc[4][4] = {};
    float sx = 0.f, sy = 0.f;

    float4 VA[4], VB[4];
#pragma unroll
    for (int q = 0; q < 4; ++q) {
        VA[q] = *(const float4*)(xp + q * 4);
        VB[q] = *(const float4*)(yp + q * 4);
    }

    for (int kk = 0; kk < Kchunk; kk += 32) {
        // convert current staged registers to hi/lo fp16, accumulate norms
        _Float16 ha[16], la[16], hb[16], lb[16];
        const float* fa = (const float*)VA;
        const float* fb = (const float*)VB;
#pragma unroll
        for (int e = 0; e < 16; ++e) {
            float v = fa[e];
            _Float16 h = (_Float16)v;
            float r = v - (float)h;
            ha[e] = h; la[e] = (_Float16)r;
            sx += v * v;
            float w = fb[e];
            _Float16 h2 = (_Float16)w;
            float r2 = w - (float)h2;
            hb[e] = h2; lb[e] = (_Float16)r2;
            sy += w * w;
        }

        __syncthreads();   // previous iteration's fragment reads complete
        *(f16x8*)&aH[srow][skq]     = *(f16x8*)&ha[0];
        *(f16x8*)&aH[srow][skq + 8] = *(f16x8*)&ha[8];
        *(f16x8*)&aL[srow][skq]     = *(f16x8*)&la[0];
        *(f16x8*)&aL[srow][skq + 8] = *(f16x8*)&la[8];
        *(f16x8*)&bH[srow][skq]     = *(f16x8*)&hb[0];
        *(f16x8*)&bH[srow][skq + 8] = *(f16x8*)&hb[8];
        *(f16x8*)&bL[srow][skq]     = *(f16x8*)&lb[0];
        *(f16x8*)&bL[srow][skq + 8] = *(f16x8*)&lb[8];

        // issue next step's global loads (overlap with MFMA below)
        if (kk + 32 < Kchunk) {
#pragma unroll
            for (int q = 0; q < 4; ++q) {
                VA[q] = *(const float4*)(xp + kk + 32 + q * 4);
                VB[q] = *(const float4*)(yp + kk + 32 + q * 4);
            }
        }
        __syncthreads();   // LDS tiles ready

        // fragment loads: lane l -> row (l&15), k-offset (l>>4)*8
        int fr = lane & 15, fk = (lane >> 4) * 8;
        f16x8 fAH[4], fAL[4], fBH[4], fBL[4];
#pragma unroll
        for (int mf = 0; mf < 4; ++mf) {
            fAH[mf] = *(const f16x8*)&aH[wm * 64 + mf * 16 + fr][fk];
            fAL[mf] = *(const f16x8*)&aL[wm * 64 + mf * 16 + fr][fk];
        }
#pragma unroll
        for (int nf = 0; nf < 4; ++nf) {
            fBH[nf] = *(const f16x8*)&bH[wn * 64 + nf * 16 + fr][fk];
            fBL[nf] = *(const f16x8*)&bL[wn * 64 + nf * 16 + fr][fk];
        }
#pragma unroll
        for (int mf = 0; mf < 4; ++mf)
#pragma unroll
            for (int nf = 0; nf < 4; ++nf) {
                acc[mf][nf] = __builtin_amdgcn_mfma_f32_16x16x32_f16(fAH[mf], fBH[nf], acc[mf][nf], 0, 0, 0);
                acc[mf][nf] = __builtin_amdgcn_mfma_f32_16x16x32_f16(fAH[mf], fBL[nf], acc[mf][nf], 0, 0, 0);
                acc[mf][nf] = __builtin_amdgcn_mfma_f32_16x16x32_f16(fAL[mf], fBH[nf], acc[mf][nf], 0, 0, 0);
            }
    }

    // write G partial; C-layout: col = lane&15, row = (lane>>4)*4 + reg
    size_t gb = ((size_t)(ks * B_ + b) * C_ + it * 128) * C_ + jt * 128;
#pragma unroll
    for (int mf = 0; mf < 4; ++mf)
#pragma unroll
        for (int nf = 0; nf < 4; ++nf) {
            int rr = wm * 64 + mf * 16 + (lane >> 4) * 4;
            int cc = wn * 64 + nf * 16 + (lane & 15);
#pragma unroll
            for (int r = 0; r < 4; ++r)
                Gp[gb + (size_t)(rr + r) * C_ + cc] = acc[mf][nf][r];
        }

    // norm partials: pair-reduce threads (2r, 2r+1) which staged one row
    sx += __shfl_xor(sx, 1);
    sy += __shfl_xor(sy, 1);
    if (!(t & 1)) {
        if (jt == 0) x2p[(ks * B_ + b) * C_ + it * 128 + srow] = sx;
        if (it == 0) y2p[(ks * B_ + b) * C_ + jt * 128 + srow] = sy;
    }
}

// ---------------- kernel 2: reduce split-K, d2 = x2+y2-2G, argmin over j (tie -> smaller j) ----------------
__global__ __launch_bounds__(256) void argmin_kernel(const float* __restrict__ Gp,
                                                     const float* __restrict__ x2p,
                                                     const float* __restrict__ y2p,
                                                     float* __restrict__ minval,
                                                     int* __restrict__ minidx,
                                                     int KS) {
    int bi = blockIdx.x;           // b*C + i
    int b = bi >> 8;
    int i = bi & 255;
    int j = threadIdx.x;           // 0..255 == C

    float g = 0.f, sx = 0.f, sy = 0.f;
    for (int ks = 0; ks < KS; ++ks) {
        g  += Gp[((size_t)(ks * B_ + b) * C_ + i) * C_ + j];
        sx += x2p[(ks * B_ + b) * C_ + i];
        sy += y2p[(ks * B_ + b) * C_ + j];
    }

    float v = sx + sy - 2.f * g;
    int idx = j;
#pragma unroll
    for (int off = 32; off > 0; off >>= 1) {
        float v2 = __shfl_down(v, off);
        int i2 = __shfl_down(idx, off);
        if (v2 < v || (v2 == v && i2 < idx)) { v = v2; idx = i2; }
    }
    __shared__ float wv[4];
    __shared__ int wi[4];
    int lane = threadIdx.x & 63, wid = threadIdx.x >> 6;
    if (lane == 0) { wv[wid] = v; wi[wid] = idx; }
    __syncthreads();
    if (threadIdx.x == 0) {
        for (int w = 1; w < 4; ++w)
            if (wv[w] < v || (wv[w] == v && wi[w] < idx)) { v = wv[w]; idx = wi[w]; }
        minval[bi] = v;
        minidx[bi] = idx;
    }
}

// ---------------- kernel 3: per-batch stable top-128 selection + compaction ----------------
__global__ __launch_bounds__(256) void select_kernel(const float* __restrict__ minval,
                                                     const int* __restrict__ minidx,
                                                     int* __restrict__ nn) {
    int b = blockIdx.x;
    int i = threadIdx.x;           // channel
    __shared__ float vals[C_];
    __shared__ int wcnt[4];

    float v = minval[b * C_ + i];
    vals[i] = v;
    __syncthreads();

    int rank = 0;
    for (int tt = 0; tt < C_; ++tt) {
        float u = vals[tt];
        rank += (u < v) || (u == v && tt < i);
    }
    bool flag = rank < NM_;

    unsigned long long m = __ballot(flag);
    int lane = i & 63, wid = i >> 6;
    if (lane == 0) wcnt[wid] = (int)__popcll(m);
    __syncthreads();
    int off = 0;
    for (int w = 0; w < wid; ++w) off += wcnt[w];
    int pos = off + (int)__popcll(m & ((1ULL << lane) - 1ULL));
    if (flag) nn[b * NM_ + pos] = minidx[b * C_ + i];
}

// ---------------- kernel 4: gather selected Ym rows ----------------
__global__ __launch_bounds__(256) void gather_kernel(const float* __restrict__ Y,
                                                     const int* __restrict__ nn,
                                                     float* __restrict__ out) {
    int blk = blockIdx.x;
    int b = blk >> 7;
    int m = blk & 127;
    int src = nn[b * NM_ + m];
    const float4* s = (const float4*)(Y + ((size_t)b * C_ + src) * N_);
    float4* d = (float4*)(out + ((size_t)b * NM_ + m) * N_);
    for (int tt = threadIdx.x; tt < N_ / 4; tt += 256) d[tt] = s[tt];
}

extern "C" void kernel_launch(void* const* d_in, const int* in_sizes, int n_in,
                              void* d_out, int out_size, void* d_ws, size_t ws_size,
                              hipStream_t stream) {
    const float* X = (const float*)d_in[0];
    const float* Y = (const float*)d_in[1];
    float* out = (float*)d_out;

    // choose split-K factor by available workspace
    size_t favail = ws_size / 4;
    int KS = 1;
    while (KS < 16) {
        size_t need = (size_t)(KS * 2) * B_ * C_ * C_      // Gp
                    + (size_t)(KS * 2) * 2 * B_ * C_       // x2p, y2p
                    + 2 * B_ * C_ + B_ * NM_;              // minval/minidx/nn
        if (need > favail) break;
        KS *= 2;
    }
    int Kchunk = N_ / KS;

    float* minval = (float*)d_ws;
    int* minidx = (int*)(minval + B_ * C_);
    int* nn = minidx + B_ * C_;
    float* x2p = (float*)(nn + B_ * NM_);
    float* y2p = x2p + (size_t)KS * B_ * C_;
    float* Gp = y2p + (size_t)KS * B_ * C_;

    hipLaunchKernelGGL(gemm_f16_kernel, dim3(KS * 32), dim3(256), 0, stream, X, Y, Gp, x2p, y2p, Kchunk);
    hipLaunchKernelGGL(argmin_kernel, dim3(B_ * C_), dim3(256), 0, stream, Gp, x2p, y2p, minval, minidx, KS);
    hipLaunchKernelGGL(select_kernel, dim3(B_), dim3(256), 0, stream, minval, minidx, nn);
    hipLaunchKernelGGL(gather_kernel, dim3(B_ * NM_), dim3(256), 0, stream, Y, nn, out);
}